// Round 1
// baseline (101.519 us; speedup 1.0000x reference)
//
#include <hip/hip_runtime.h>
#include <math.h>

#define NB 32
#define NA 5
#define NC 8
#define NH 32
#define NW 64
#define NT 50
#define NCH (7 + NC)                 // 15 channels per anchor
#define HW (NH * NW)                 // 2048
#define M_CELLS (NB * NA * NH * NW)  // 327680
#define OBJECT_SCALE 10.0f
#define SIL_THRESH 0.6f

__constant__ float c_anchors[NA * 2] = {
    1.08f, 1.19f, 3.42f, 4.41f, 6.63f, 11.38f, 9.42f, 5.11f, 16.62f, 10.52f};

__device__ __forceinline__ float sigmoidf(float v) {
    return 1.0f / (1.0f + expf(-v));
}

// IoU of two (cx, cy, w, h) boxes, reference-exact formulation.
__device__ __forceinline__ float iou_cxcywh(float ax, float ay, float aw, float ah,
                                            float bx, float by, float bw, float bh) {
    float mx = fminf(ax - aw * 0.5f, bx - bw * 0.5f);
    float Mx = fmaxf(ax + aw * 0.5f, bx + bw * 0.5f);
    float my = fminf(ay - ah * 0.5f, by - bh * 0.5f);
    float My = fmaxf(ay + ah * 0.5f, by + bh * 0.5f);
    float cw = aw + bw - (Mx - mx);
    float ch = ah + bh - (My - my);
    float inter = (cw > 0.0f && ch > 0.0f) ? cw * ch : 0.0f;
    float uni = aw * ah + bw * bh - inter;
    return inter / uni;
}

// Re-poisoned every replay: re-init scratch + output each call.
__global__ void init_kernel(int* __restrict__ tidx, float* __restrict__ out, int out_size) {
    int idx = blockIdx.x * blockDim.x + threadIdx.x;
    if (idx < M_CELLS) tidx[idx] = -1;
    if (idx < out_size) out[idx] = 0.0f;
}

// Per-target: validity (cumprod), gt box, best anchor, scatter last-valid-t per cell.
// tinfo layout per (b,t): [gx, gy, gw, gl, cls, tim, tre, valid]
__global__ void target_kernel(const float* __restrict__ target,
                              int* __restrict__ tidx,
                              float* __restrict__ tinfo) {
    int b = blockIdx.x;
    int t = threadIdx.x;
    if (t >= NT) return;
    const float* tp = target + (b * NT + t) * 7;

    bool valid = true;
    for (int tt = 0; tt <= t; ++tt) {
        if (target[(b * NT + tt) * 7 + 1] == 0.0f) { valid = false; break; }
    }

    float gx = tp[1] * (float)NW;
    float gy = tp[2] * (float)NH;
    float gw = tp[3] * (float)NW;
    float gl = tp[4] * (float)NH;

    float* ti = tinfo + (b * NT + t) * 8;
    ti[0] = gx; ti[1] = gy; ti[2] = gw; ti[3] = gl;
    ti[4] = tp[0]; ti[5] = tp[5]; ti[6] = tp[6];
    ti[7] = valid ? 1.0f : 0.0f;
    if (!valid) return;

    // argmax anchor IoU (co-centered); strict > keeps first max like jnp.argmax
    int best_n = 0;
    float best = -1.0f;
    for (int a = 0; a < NA; ++a) {
        float aw = c_anchors[2 * a], al = c_anchors[2 * a + 1];
        float inter = fminf(gw, aw) * fminf(gl, al);
        float uni = gw * gl + aw * al - inter;
        float iou = inter / uni;
        if (iou > best) { best = iou; best_n = a; }
    }

    int gi = min(max((int)gx, 0), NW - 1);
    int gj = min(max((int)gy, 0), NH - 1);
    int lin = ((b * NA + best_n) * NH + gj) * NW + gi;
    atomicMax(&tidx[lin], t);   // segment_max over t per cell
}

__global__ __launch_bounds__(256) void cell_kernel(const float* __restrict__ output,
                                                   const float* __restrict__ tinfo,
                                                   const int* __restrict__ tidx,
                                                   float* __restrict__ out) {
    const int blocks_per_b = (NA * HW) / 256;   // 40
    int b = blockIdx.x / blocks_per_b;
    int m_local = (blockIdx.x % blocks_per_b) * 256 + threadIdx.x;
    int a = m_local / HW;
    int rem = m_local - a * HW;
    int j = rem / NW;
    int i = rem - j * NW;

    __shared__ float s_t[NT][8];
    for (int idx = threadIdx.x; idx < NT * 8; idx += 256)
        ((float*)s_t)[idx] = tinfo[b * NT * 8 + idx];
    __syncthreads();

    // 15 channel loads, each coalesced (wave = one full i-row)
    const float* op = output + ((size_t)(b * NA + a) * NCH) * HW + j * NW + i;
    float o[NCH];
#pragma unroll
    for (int c = 0; c < NCH; ++c) o[c] = op[(size_t)c * HW];

    float x = sigmoidf(o[0]);
    float y = sigmoidf(o[1]);
    float w = o[2], l = o[3], im = o[4], re = o[5];
    float conf = sigmoidf(o[6]);

    float aw = c_anchors[2 * a], al = c_anchors[2 * a + 1];
    float pbx = x + (float)i;
    float pby = y + (float)j;
    float pbw = expf(w) * aw;
    float pbl = expf(l) * al;

    // max IoU over this batch's valid targets (validity is monotone -> break)
    float max_iou = 0.0f;
    for (int t = 0; t < NT; ++t) {
        if (s_t[t][7] == 0.0f) break;
        float iou = iou_cxcywh(s_t[t][0], s_t[t][1], s_t[t][2], s_t[t][3],
                               pbx, pby, pbw, pbl);
        max_iou = fmaxf(max_iou, iou);
    }

    float conf_mask = (max_iou > SIL_THRESH) ? 0.0f : 1.0f;  // NOOBJECT_SCALE=1
    float loss = 0.0f;
    float tconf = 0.0f;

    int t = tidx[((b * NA + a) * NH + j) * NW + i];
    if (t >= 0) {
        float gx = s_t[t][0], gy = s_t[t][1], gw = s_t[t][2], gl = s_t[t][3];
        float tx = gx - (float)i;
        float ty = gy - (float)j;
        float tw = logf(gw / aw);
        float tl = logf(gl / al);
        float tim = s_t[t][5], tre = s_t[t][6];
        tconf = iou_cxcywh(gx, gy, gw, gl, pbx, pby, pbw, pbl);
        conf_mask = OBJECT_SCALE;

        float dx = x - tx, dy = y - ty, dw = w - tw, dl = l - tl;
        float di = im - tim, dr = re - trunc(0.0f) * 0.0f - tre;  // (plain im/re MSE)
        dr = re - tre;
        loss += dx * dx + dy * dy + dw * dw + dl * dl + di * di + dr * dr;

        // cross-entropy: logsumexp(logits) - logits[tcls]
        int tcls = (int)s_t[t][4];           // trunc like astype(int32)
        tcls = min(max(tcls, 0), NC - 1);
        float mx = o[7];
#pragma unroll
        for (int c = 1; c < NC; ++c) mx = fmaxf(mx, o[7 + c]);
        float s = 0.0f;
#pragma unroll
        for (int c = 0; c < NC; ++c) s += expf(o[7 + c] - mx);
        loss += (mx + logf(s)) - o[7 + tcls];
    }

    float d = conf * conf_mask - tconf * conf_mask;
    loss += d * d;

    // wave (64) shuffle reduce, then cross-wave via LDS, one atomic per block
    for (int off = 32; off > 0; off >>= 1)
        loss += __shfl_down(loss, off, 64);
    __shared__ float s_part[4];
    int wave = threadIdx.x >> 6;
    int lane = threadIdx.x & 63;
    if (lane == 0) s_part[wave] = loss;
    __syncthreads();
    if (threadIdx.x == 0) {
        atomicAdd(out, s_part[0] + s_part[1] + s_part[2] + s_part[3]);
    }
}

extern "C" void kernel_launch(void* const* d_in, const int* in_sizes, int n_in,
                              void* d_out, int out_size, void* d_ws, size_t ws_size,
                              hipStream_t stream) {
    const float* output = (const float*)d_in[0];
    const float* target = (const float*)d_in[1];
    float* out = (float*)d_out;
    int* tidx = (int*)d_ws;
    float* tinfo = (float*)((char*)d_ws + (size_t)M_CELLS * sizeof(int));

    hipLaunchKernelGGL(init_kernel, dim3((M_CELLS + 255) / 256), dim3(256), 0, stream,
                       tidx, out, out_size);
    hipLaunchKernelGGL(target_kernel, dim3(NB), dim3(64), 0, stream,
                       target, tidx, tinfo);
    hipLaunchKernelGGL(cell_kernel, dim3(NB * 40), dim3(256), 0, stream,
                       output, tinfo, tidx, out);
}

// Round 2
// 95.083 us; speedup vs baseline: 1.0677x; 1.0677x over previous
//
#include <hip/hip_runtime.h>
#include <math.h>

#define NB 32
#define NA 5
#define NC 8
#define NH 32
#define NW 64
#define NT 50
#define NCH (7 + NC)                 // 15 channels per anchor
#define HW (NH * NW)                 // 2048
#define OBJECT_SCALE 10.0f

__constant__ float c_anchors[NA * 2] = {
    1.08f, 1.19f, 3.42f, 4.41f, 6.63f, 11.38f, 9.42f, 5.11f, 16.62f, 10.52f};

__device__ __forceinline__ float sigmoidf(float v) {
    return 1.0f / (1.0f + expf(-v));
}

// ---------------------------------------------------------------------------
// Prep: one wave per batch. Computes per-target corner boxes, best anchor,
// assignment code, and precomputed regression targets. Also zeroes d_out.
// tinfo layout per (b,t), 16 floats:
//  [0]tlx [1]thx [2]tly [3]thy [4]gw [5]gl [6]area [7]code
//  [8]tx  [9]ty  [10]im [11]re [12]cls [13]tw_log [14]tl_log [15]unused
// ---------------------------------------------------------------------------
__global__ void prep_kernel(const float* __restrict__ target,
                            int* __restrict__ nvalid,
                            float* __restrict__ tinfo,
                            float* __restrict__ out) {
    int b = blockIdx.x;
    int t = threadIdx.x;  // 64 threads, one wave
    const float* tp = target + (size_t)(b * NT + t) * 7;

    float t0 = 0.f, t1 = 0.f, t2 = 0.f, t3 = 0.f, t4 = 0.f, t5 = 0.f, t6 = 0.f;
    if (t < NT) {
        t0 = tp[0]; t1 = tp[1]; t2 = tp[2]; t3 = tp[3];
        t4 = tp[4]; t5 = tp[5]; t6 = tp[6];
    }
    // validity = cumprod(tgt[...,1] != 0): monotone prefix -> count trailing ones
    unsigned long long bal = __ballot(t < NT && t1 != 0.0f);
    if (t == 0) {
        int nv = __ffsll((unsigned long long)~bal) - 1;  // trailing-ones count
        nvalid[b] = nv;
        if (b == 0) out[0] = 0.0f;  // d_out re-poisoned each replay
    }
    if (t >= NT) return;

    float gx = t1 * (float)NW;
    float gy = t2 * (float)NH;
    float gw = t3 * (float)NW;
    float gl = t4 * (float)NH;

    // argmax anchor IoU (co-centered); strict > keeps first max like jnp.argmax
    int best_n = 0;
    float best = -1.0f;
#pragma unroll
    for (int a = 0; a < NA; ++a) {
        float aw = c_anchors[2 * a], al = c_anchors[2 * a + 1];
        float inter = fminf(gw, aw) * fminf(gl, al);
        float uni = gw * gl + aw * al - inter;
        float iou = inter / uni;
        if (iou > best) { best = iou; best_n = a; }
    }
    float aw = c_anchors[2 * best_n], al = c_anchors[2 * best_n + 1];

    int gi = min(max((int)gx, 0), NW - 1);   // trunc like astype(int32)
    int gj = min(max((int)gy, 0), NH - 1);

    float* ti = tinfo + (size_t)(b * NT + t) * 16;
    ti[0] = gx - gw * 0.5f;
    ti[1] = gx + gw * 0.5f;
    ti[2] = gy - gl * 0.5f;
    ti[3] = gy + gl * 0.5f;
    ti[4] = gw;
    ti[5] = gl;
    ti[6] = gw * gl;
    ti[7] = (float)((best_n << 12) | (gj << 6) | gi);  // < 2^15, exact in fp32
    ti[8] = gx - (float)gi;
    ti[9] = gy - (float)gj;
    ti[10] = t5;
    ti[11] = t6;
    ti[12] = t0;
    ti[13] = logf(gw / aw);
    ti[14] = logf(gl / al);
    ti[15] = 0.f;
}

// ---------------------------------------------------------------------------
// Main: one thread per cell (b,a,j,i). Target loop is wave-uniform scalar
// data (s_load) + ~20 VALU ops/iter, no division, no LDS in the loop.
// ---------------------------------------------------------------------------
__global__ __launch_bounds__(256) void cell_kernel(const float* __restrict__ output,
                                                   const float* __restrict__ tinfo,
                                                   const int* __restrict__ nvalid,
                                                   float* __restrict__ out) {
    const int blocks_per_b = (NA * HW) / 256;  // 40
    int b = blockIdx.x / blocks_per_b;
    int m = (blockIdx.x % blocks_per_b) * 256 + threadIdx.x;
    int a = m >> 11;          // / HW (uniform per block: 256 | 2048)
    int rem = m & (HW - 1);
    int j = rem >> 6;
    int i = rem & (NW - 1);

    // 15 channel loads, each coalesced (wave = one full i-row)
    const float* op = output + (size_t)(b * NA + a) * NCH * HW + (j << 6) + i;
    float o[NCH];
#pragma unroll
    for (int c = 0; c < NCH; ++c) o[c] = op[(size_t)c * HW];

    float x = sigmoidf(o[0]);
    float y = sigmoidf(o[1]);
    float conf = sigmoidf(o[6]);

    float aw = c_anchors[2 * a], al = c_anchors[2 * a + 1];
    float pbx = x + (float)i;
    float pby = y + (float)j;
    float pbw = expf(o[2]) * aw;
    float pbl = expf(o[3]) * al;

    float plx = pbx - pbw * 0.5f;
    float phx = pbx + pbw * 0.5f;
    float ply = pby - pbl * 0.5f;
    float phy = pby + pbl * 0.5f;
    float parea = pbw * pbl;
    float mycode = (float)((a << 12) | (j << 6) | i);

    int nv = nvalid[b];
    const float* tb = tinfo + (size_t)b * NT * 16;

    float silm = -1.0f;   // max(inter - 0.6*union): >0 <=> max_iou > 0.6
    int ta = -1;          // last matching valid t == segment_max semantics
    for (int t = 0; t < nv; ++t) {
        const float* ti = tb + t * 16;
        float tlx = ti[0], thx = ti[1], tly = ti[2], thy = ti[3];
        float gw = ti[4], gl = ti[5], tarea = ti[6], code = ti[7];
        float mx = fminf(tlx, plx);
        float Mx = fmaxf(thx, phx);
        float my = fminf(tly, ply);
        float My = fmaxf(thy, phy);
        float cw = (gw + pbw) - (Mx - mx);
        float ch = (gl + pbl) - (My - my);
        float inter = (cw > 0.0f && ch > 0.0f) ? cw * ch : 0.0f;
        float uni = tarea + parea - inter;
        silm = fmaxf(silm, inter - 0.6f * uni);  // union > 0 always
        if (code == mycode) ta = t;
    }

    float loss;
    if (ta >= 0) {
        const float* ti = tb + (size_t)ta * 16;
        float tlx = ti[0], thx = ti[1], tly = ti[2], thy = ti[3];
        float gw = ti[4], gl = ti[5], tarea = ti[6];
        // tconf = IoU(gt, pred) — exact division, rare path
        float mx = fminf(tlx, plx);
        float Mx = fmaxf(thx, phx);
        float my = fminf(tly, ply);
        float My = fmaxf(thy, phy);
        float cw = (gw + pbw) - (Mx - mx);
        float ch = (gl + pbl) - (My - my);
        float inter = (cw > 0.0f && ch > 0.0f) ? cw * ch : 0.0f;
        float tconf = inter / (tarea + parea - inter);

        float dx = x - ti[8];
        float dy = y - ti[9];
        float dw = o[2] - ti[13];
        float dl = o[3] - ti[14];
        float di = o[4] - ti[10];
        float dr = o[5] - ti[11];
        loss = dx * dx + dy * dy + dw * dw + dl * dl + di * di + dr * dr;

        float dc = OBJECT_SCALE * (conf - tconf);
        loss += dc * dc;

        // cross-entropy: logsumexp(logits) - logits[tcls]
        int tcls = min(max((int)ti[12], 0), NC - 1);
        float mxl = o[7];
#pragma unroll
        for (int c = 1; c < NC; ++c) mxl = fmaxf(mxl, o[7 + c]);
        float s = 0.0f;
#pragma unroll
        for (int c = 0; c < NC; ++c) s += expf(o[7 + c] - mxl);
        loss += (mxl + logf(s)) - o[7 + tcls];
    } else {
        loss = (silm > 0.0f) ? 0.0f : conf * conf;  // NOOBJECT_SCALE = 1
    }

    // wave (64) shuffle reduce, then cross-wave via LDS, one atomic per block
    for (int off = 32; off > 0; off >>= 1)
        loss += __shfl_down(loss, off, 64);
    __shared__ float s_part[4];
    int wave = threadIdx.x >> 6;
    int lane = threadIdx.x & 63;
    if (lane == 0) s_part[wave] = loss;
    __syncthreads();
    if (threadIdx.x == 0)
        atomicAdd(out, s_part[0] + s_part[1] + s_part[2] + s_part[3]);
}

extern "C" void kernel_launch(void* const* d_in, const int* in_sizes, int n_in,
                              void* d_out, int out_size, void* d_ws, size_t ws_size,
                              hipStream_t stream) {
    const float* output = (const float*)d_in[0];
    const float* target = (const float*)d_in[1];
    float* out = (float*)d_out;
    int* nvalid = (int*)d_ws;                                   // 32 ints
    float* tinfo = (float*)((char*)d_ws + 128);                 // 32*50*16 floats

    hipLaunchKernelGGL(prep_kernel, dim3(NB), dim3(64), 0, stream,
                       target, nvalid, tinfo, out);
    hipLaunchKernelGGL(cell_kernel, dim3(NB * 40), dim3(256), 0, stream,
                       output, tinfo, nvalid, out);
}

// Round 3
// 92.071 us; speedup vs baseline: 1.1026x; 1.0327x over previous
//
#include <hip/hip_runtime.h>
#include <math.h>

#define NB 32
#define NA 5
#define NC 8
#define NH 32
#define NW 64
#define NT 50
#define NCH (7 + NC)                 // 15 channels per anchor
#define HW (NH * NW)                 // 2048
#define OBJECT_SCALE 10.0f

__constant__ float c_anchors[NA * 2] = {
    1.08f, 1.19f, 3.42f, 4.41f, 6.63f, 11.38f, 9.42f, 5.11f, 16.62f, 10.52f};

__device__ __forceinline__ float fast_exp(float v) { return __expf(v); }
__device__ __forceinline__ float fast_log(float v) { return __logf(v); }
__device__ __forceinline__ float fast_sigmoid(float v) {
    return __builtin_amdgcn_rcpf(1.0f + __expf(-v));
}

// ---------------------------------------------------------------------------
// Prep: one wave per batch. Per-target corner boxes, best anchor, assignment
// code, regression targets. Also zeroes d_out (re-poisoned each replay).
// tinfo layout per (b,t), 16 floats:
//  [0]tlx [1]thx [2]tly [3]thy [4]gw [5]gl [6]0.6*area [7]code
//  [8]tx  [9]ty  [10]im [11]re [12]cls [13]tw_log [14]tl_log [15]area
// ---------------------------------------------------------------------------
__global__ void prep_kernel(const float* __restrict__ target,
                            int* __restrict__ nvalid,
                            float* __restrict__ tinfo,
                            float* __restrict__ out) {
    int b = blockIdx.x;
    int t = threadIdx.x;  // 64 threads, one wave
    const float* tp = target + (size_t)(b * NT + t) * 7;

    float t0 = 0.f, t1 = 0.f, t2 = 0.f, t3 = 0.f, t4 = 0.f, t5 = 0.f, t6 = 0.f;
    if (t < NT) {
        t0 = tp[0]; t1 = tp[1]; t2 = tp[2]; t3 = tp[3];
        t4 = tp[4]; t5 = tp[5]; t6 = tp[6];
    }
    // validity = cumprod(tgt[...,1] != 0): monotone prefix -> count trailing ones
    unsigned long long bal = __ballot(t < NT && t1 != 0.0f);
    if (t == 0) {
        int nv = __ffsll((unsigned long long)~bal) - 1;  // trailing-ones count
        nvalid[b] = nv;
        if (b == 0) out[0] = 0.0f;
    }
    if (t >= NT) return;

    float gx = t1 * (float)NW;
    float gy = t2 * (float)NH;
    float gw = t3 * (float)NW;
    float gl = t4 * (float)NH;

    // argmax anchor IoU (co-centered); strict > keeps first max like jnp.argmax
    int best_n = 0;
    float best = -1.0f;
#pragma unroll
    for (int a = 0; a < NA; ++a) {
        float aw = c_anchors[2 * a], al = c_anchors[2 * a + 1];
        float inter = fminf(gw, aw) * fminf(gl, al);
        float uni = gw * gl + aw * al - inter;
        float iou = inter / uni;
        if (iou > best) { best = iou; best_n = a; }
    }
    float aw = c_anchors[2 * best_n], al = c_anchors[2 * best_n + 1];

    int gi = min(max((int)gx, 0), NW - 1);   // trunc like astype(int32)
    int gj = min(max((int)gy, 0), NH - 1);

    float* ti = tinfo + (size_t)(b * NT + t) * 16;
    float area = gw * gl;
    ti[0] = gx - gw * 0.5f;
    ti[1] = gx + gw * 0.5f;
    ti[2] = gy - gl * 0.5f;
    ti[3] = gy + gl * 0.5f;
    ti[4] = gw;
    ti[5] = gl;
    ti[6] = 0.6f * area;
    ti[7] = (float)((best_n << 12) | (gj << 6) | gi);  // < 2^15, exact in fp32
    ti[8] = gx - (float)gi;
    ti[9] = gy - (float)gj;
    ti[10] = t5;
    ti[11] = t6;
    ti[12] = t0;
    ti[13] = fast_log(gw / aw);
    ti[14] = fast_log(gl / al);
    ti[15] = area;
}

// ---------------------------------------------------------------------------
// Main: one thread per cell (b,a,j,i). Target loop is wave-uniform scalar
// data (s_load) + ~15 VALU ops/iter; cls channels loaded lazily.
// ---------------------------------------------------------------------------
__global__ __launch_bounds__(256) void cell_kernel(const float* __restrict__ output,
                                                   const float* __restrict__ tinfo,
                                                   const int* __restrict__ nvalid,
                                                   float* __restrict__ out) {
    const int blocks_per_b = (NA * HW) / 256;  // 40
    int b = blockIdx.x / blocks_per_b;
    int m = (blockIdx.x % blocks_per_b) * 256 + threadIdx.x;
    int a = m >> 11;          // / HW (uniform per block: 256 | 2048)
    int rem = m & (HW - 1);
    int j = rem >> 6;
    int i = rem & (NW - 1);

    // 7 always-needed channel loads, each coalesced (wave = one full i-row)
    const float* op = output + (size_t)(b * NA + a) * NCH * HW + (j << 6) + i;
    float o0 = op[0 * HW], o1 = op[1 * HW], o2 = op[2 * HW], o3 = op[3 * HW];
    float o4 = op[4 * HW], o5 = op[5 * HW], o6 = op[6 * HW];

    float x = fast_sigmoid(o0);
    float y = fast_sigmoid(o1);
    float conf = fast_sigmoid(o6);

    float aw = c_anchors[2 * a], al = c_anchors[2 * a + 1];
    float pbx = x + (float)i;
    float pby = y + (float)j;
    float pbw = fast_exp(o2) * aw;
    float pbl = fast_exp(o3) * al;

    float plx = pbx - pbw * 0.5f;
    float phx = pbx + pbw * 0.5f;
    float ply = pby - pbl * 0.5f;
    float phy = pby + pbl * 0.5f;
    float parea = pbw * pbl;
    float mycode = (float)((a << 12) | (j << 6) | i);

    int nv = nvalid[b];
    const float* tb = tinfo + (size_t)b * NT * 16;

    // silm = max_t(1.6*inter - 0.6*tarea); silenced <=> silm > 0.6*parea
    float silm = -1e30f;
    int ta = -1;          // last matching valid t == segment_max semantics
    for (int t = 0; t < nv; ++t) {
        const float* ti = tb + t * 16;
        float tlx = ti[0], thx = ti[1], tly = ti[2], thy = ti[3];
        float gw = ti[4], gl = ti[5], ct = ti[6], code = ti[7];
        float mx = fminf(tlx, plx);
        float Mx = fmaxf(thx, phx);
        float my = fminf(tly, ply);
        float My = fmaxf(thy, phy);
        float cw = gw + pbw - (Mx - mx);
        float ch = gl + pbl - (My - my);
        float inter = fmaxf(cw, 0.0f) * fmaxf(ch, 0.0f);
        silm = fmaxf(silm, 1.6f * inter - ct);
        if (code == mycode) ta = t;
    }

    float loss;
    if (ta >= 0) {
        const float* ti = tb + (size_t)ta * 16;
        float tlx = ti[0], thx = ti[1], tly = ti[2], thy = ti[3];
        float gw = ti[4], gl = ti[5], tarea = ti[15];
        // tconf = IoU(gt, pred) — rare path
        float mx = fminf(tlx, plx);
        float Mx = fmaxf(thx, phx);
        float my = fminf(tly, ply);
        float My = fmaxf(thy, phy);
        float cw = gw + pbw - (Mx - mx);
        float ch = gl + pbl - (My - my);
        float inter = fmaxf(cw, 0.0f) * fmaxf(ch, 0.0f);
        float tconf = inter / (tarea + parea - inter);

        float dx = x - ti[8];
        float dy = y - ti[9];
        float dw = o2 - ti[13];
        float dl = o3 - ti[14];
        float di = o4 - ti[10];
        float dr = o5 - ti[11];
        loss = dx * dx + dy * dy + dw * dw + dl * dl + di * di + dr * dr;

        float dc = OBJECT_SCALE * (conf - tconf);
        loss += dc * dc;

        // cross-entropy: logsumexp(logits) - logits[tcls]; lazy cls loads
        float cl[NC];
#pragma unroll
        for (int c = 0; c < NC; ++c) cl[c] = op[(size_t)(7 + c) * HW];
        int tcls = min(max((int)ti[12], 0), NC - 1);
        float mxl = cl[0];
#pragma unroll
        for (int c = 1; c < NC; ++c) mxl = fmaxf(mxl, cl[c]);
        float s = 0.0f;
#pragma unroll
        for (int c = 0; c < NC; ++c) s += fast_exp(cl[c] - mxl);
        loss += (mxl + fast_log(s)) - cl[tcls];
    } else {
        bool silenced = silm > 0.6f * parea;   // <=> max_iou > 0.6
        loss = silenced ? 0.0f : conf * conf;  // NOOBJECT_SCALE = 1
    }

    // wave (64) shuffle reduce, then cross-wave via LDS, one atomic per block
    for (int off = 32; off > 0; off >>= 1)
        loss += __shfl_down(loss, off, 64);
    __shared__ float s_part[4];
    int wave = threadIdx.x >> 6;
    int lane = threadIdx.x & 63;
    if (lane == 0) s_part[wave] = loss;
    __syncthreads();
    if (threadIdx.x == 0)
        atomicAdd(out, s_part[0] + s_part[1] + s_part[2] + s_part[3]);
}

extern "C" void kernel_launch(void* const* d_in, const int* in_sizes, int n_in,
                              void* d_out, int out_size, void* d_ws, size_t ws_size,
                              hipStream_t stream) {
    const float* output = (const float*)d_in[0];
    const float* target = (const float*)d_in[1];
    float* out = (float*)d_out;
    int* nvalid = (int*)d_ws;                                   // 32 ints
    float* tinfo = (float*)((char*)d_ws + 128);                 // 32*50*16 floats

    hipLaunchKernelGGL(prep_kernel, dim3(NB), dim3(64), 0, stream,
                       target, nvalid, tinfo, out);
    hipLaunchKernelGGL(cell_kernel, dim3(NB * 40), dim3(256), 0, stream,
                       output, tinfo, nvalid, out);
}

// Round 4
// 89.047 us; speedup vs baseline: 1.1401x; 1.0340x over previous
//
#include <hip/hip_runtime.h>
#include <math.h>

#define NB 32
#define NA 5
#define NC 8
#define NH 32
#define NW 64
#define NT 50
#define NCH (7 + NC)                 // 15 channels per anchor
#define HW (NH * NW)                 // 2048
#define OBJECT_SCALE 10.0f

__constant__ float c_anchors[NA * 2] = {
    1.08f, 1.19f, 3.42f, 4.41f, 6.63f, 11.38f, 9.42f, 5.11f, 16.62f, 10.52f};

__device__ __forceinline__ float fast_exp(float v) { return __expf(v); }
__device__ __forceinline__ float fast_log(float v) { return __logf(v); }
__device__ __forceinline__ float fast_sigmoid(float v) {
    return __builtin_amdgcn_rcpf(1.0f + __expf(-v));
}

// ---------------------------------------------------------------------------
// Prep: one wave per batch. Two records per (b,t):
//  tA (hot, read every loop iter): [tlx, thx, tly, thy, ct2=0.375*area, code, pad, pad]
//  tB (cold, assigned cells only): [tx, ty, im, re, cls, tw_log, tl_log, area]
// Also zeroes d_out (re-poisoned each replay).
// ---------------------------------------------------------------------------
__global__ void prep_kernel(const float* __restrict__ target,
                            int* __restrict__ nvalid,
                            float* __restrict__ tA,
                            float* __restrict__ tB,
                            float* __restrict__ out) {
    int b = blockIdx.x;
    int t = threadIdx.x;  // 64 threads, one wave
    const float* tp = target + (size_t)(b * NT + t) * 7;

    float t0 = 0.f, t1 = 0.f, t2 = 0.f, t3 = 0.f, t4 = 0.f, t5 = 0.f, t6 = 0.f;
    if (t < NT) {
        t0 = tp[0]; t1 = tp[1]; t2 = tp[2]; t3 = tp[3];
        t4 = tp[4]; t5 = tp[5]; t6 = tp[6];
    }
    // validity = cumprod(tgt[...,1] != 0): monotone prefix -> count trailing ones
    unsigned long long bal = __ballot(t < NT && t1 != 0.0f);
    if (t == 0) {
        int nv = __ffsll((unsigned long long)~bal) - 1;  // trailing-ones count
        nvalid[b] = nv;
        if (b == 0) out[0] = 0.0f;
    }
    if (t >= NT) return;

    float gx = t1 * (float)NW;
    float gy = t2 * (float)NH;
    float gw = t3 * (float)NW;
    float gl = t4 * (float)NH;

    // argmax anchor IoU (co-centered); strict > keeps first max like jnp.argmax
    int best_n = 0;
    float best = -1.0f;
#pragma unroll
    for (int a = 0; a < NA; ++a) {
        float aw = c_anchors[2 * a], al = c_anchors[2 * a + 1];
        float inter = fminf(gw, aw) * fminf(gl, al);
        float uni = gw * gl + aw * al - inter;
        float iou = inter / uni;
        if (iou > best) { best = iou; best_n = a; }
    }
    float aw = c_anchors[2 * best_n], al = c_anchors[2 * best_n + 1];

    int gi = min(max((int)gx, 0), NW - 1);   // trunc like astype(int32)
    int gj = min(max((int)gy, 0), NH - 1);

    float area = gw * gl;
    float* a8 = tA + (size_t)(b * NT + t) * 8;
    a8[0] = gx - gw * 0.5f;
    a8[1] = gx + gw * 0.5f;
    a8[2] = gy - gl * 0.5f;
    a8[3] = gy + gl * 0.5f;
    a8[4] = 0.375f * area;                              // 0.6/1.6
    a8[5] = (float)((best_n << 12) | (gj << 6) | gi);   // < 2^15, exact in fp32
    a8[6] = 0.f;
    a8[7] = 0.f;

    float* b8 = tB + (size_t)(b * NT + t) * 8;
    b8[0] = gx - (float)gi;
    b8[1] = gy - (float)gj;
    b8[2] = t5;
    b8[3] = t6;
    b8[4] = t0;
    b8[5] = fast_log(gw / aw);
    b8[6] = fast_log(gl / al);
    b8[7] = area;
}

// ---------------------------------------------------------------------------
// Main: one thread per cell (b,a,j,i). Loop: one s_load_dwordx8 of
// wave-uniform target data + ~12 VALU ops/iter. im/re/cls loads lazy.
// ---------------------------------------------------------------------------
__global__ __launch_bounds__(256) void cell_kernel(const float* __restrict__ output,
                                                   const float* __restrict__ tA,
                                                   const float* __restrict__ tB,
                                                   const int* __restrict__ nvalid,
                                                   float* __restrict__ out) {
    const int blocks_per_b = (NA * HW) / 256;  // 40
    int b = blockIdx.x / blocks_per_b;
    int m = (blockIdx.x % blocks_per_b) * 256 + threadIdx.x;
    int a = m >> 11;          // / HW (uniform per block: 256 | 2048)
    int rem = m & (HW - 1);
    int j = rem >> 6;
    int i = rem & (NW - 1);

    // 5 always-needed channel loads, each coalesced (wave = one full i-row)
    const float* op = output + (size_t)(b * NA + a) * NCH * HW + (j << 6) + i;
    float o0 = op[0 * HW], o1 = op[1 * HW], o2 = op[2 * HW], o3 = op[3 * HW];
    float o6 = op[6 * HW];

    float x = fast_sigmoid(o0);
    float y = fast_sigmoid(o1);
    float conf = fast_sigmoid(o6);

    float aw = c_anchors[2 * a], al = c_anchors[2 * a + 1];
    float pbx = x + (float)i;
    float pby = y + (float)j;
    float pbw = fast_exp(o2) * aw;
    float pbl = fast_exp(o3) * al;

    float plx = pbx - pbw * 0.5f;
    float phx = pbx + pbw * 0.5f;
    float ply = pby - pbl * 0.5f;
    float phy = pby + pbl * 0.5f;
    float parea = pbw * pbl;
    float mycode = (float)((a << 12) | (j << 6) | i);

    int nv = nvalid[b];
    const float* tb8 = tA + (size_t)b * NT * 8;

    // silm = max_t(inter - 0.375*tarea); silenced <=> silm > 0.375*parea
    float silm = -1e30f;
    int ta = -1;          // last matching valid t == segment_max semantics
#pragma unroll 2
    for (int t = 0; t < nv; ++t) {
        const float* ti = tb8 + t * 8;
        float tlx = ti[0], thx = ti[1], tly = ti[2], thy = ti[3];
        float ct2 = ti[4], code = ti[5];
        float cw = fminf(thx, phx) - fmaxf(tlx, plx);
        float ch = fminf(thy, phy) - fmaxf(tly, ply);
        float cwc = fmaxf(cw, 0.0f);
        float chc = fmaxf(ch, 0.0f);
        silm = fmaxf(silm, __builtin_fmaf(cwc, chc, -ct2));
        if (code == mycode) ta = t;
    }

    float loss;
    if (ta >= 0) {
        const float* ai = tb8 + (size_t)ta * 8;
        const float* bi = tB + ((size_t)b * NT + ta) * 8;
        float tlx = ai[0], thx = ai[1], tly = ai[2], thy = ai[3];
        float tarea = bi[7];
        // tconf = IoU(gt, pred) — rare path, exact division
        float cw = fminf(thx, phx) - fmaxf(tlx, plx);
        float ch = fminf(thy, phy) - fmaxf(tly, ply);
        float inter = fmaxf(cw, 0.0f) * fmaxf(ch, 0.0f);
        float tconf = inter / (tarea + parea - inter);

        float o4 = op[4 * HW], o5 = op[5 * HW];
        float dx = x - bi[0];
        float dy = y - bi[1];
        float dw = o2 - bi[5];
        float dl = o3 - bi[6];
        float di = o4 - bi[2];
        float dr = o5 - bi[3];
        loss = dx * dx + dy * dy + dw * dw + dl * dl + di * di + dr * dr;

        float dc = OBJECT_SCALE * (conf - tconf);
        loss += dc * dc;

        // cross-entropy: logsumexp(logits) - logits[tcls]; lazy cls loads
        float cl[NC];
#pragma unroll
        for (int c = 0; c < NC; ++c) cl[c] = op[(size_t)(7 + c) * HW];
        int tcls = min(max((int)bi[4], 0), NC - 1);
        float mxl = cl[0];
#pragma unroll
        for (int c = 1; c < NC; ++c) mxl = fmaxf(mxl, cl[c]);
        float s = 0.0f;
#pragma unroll
        for (int c = 0; c < NC; ++c) s += fast_exp(cl[c] - mxl);
        loss += (mxl + fast_log(s)) - cl[tcls];
    } else {
        bool silenced = silm > 0.375f * parea;  // <=> max_iou > 0.6
        loss = silenced ? 0.0f : conf * conf;   // NOOBJECT_SCALE = 1
    }

    // wave (64) shuffle reduce, then cross-wave via LDS, one atomic per block
    for (int off = 32; off > 0; off >>= 1)
        loss += __shfl_down(loss, off, 64);
    __shared__ float s_part[4];
    int wave = threadIdx.x >> 6;
    int lane = threadIdx.x & 63;
    if (lane == 0) s_part[wave] = loss;
    __syncthreads();
    if (threadIdx.x == 0)
        atomicAdd(out, s_part[0] + s_part[1] + s_part[2] + s_part[3]);
}

extern "C" void kernel_launch(void* const* d_in, const int* in_sizes, int n_in,
                              void* d_out, int out_size, void* d_ws, size_t ws_size,
                              hipStream_t stream) {
    const float* output = (const float*)d_in[0];
    const float* target = (const float*)d_in[1];
    float* out = (float*)d_out;
    int* nvalid = (int*)d_ws;                                    // 32 ints
    float* tA = (float*)((char*)d_ws + 128);                     // 32*50*8 floats
    float* tB = tA + (size_t)NB * NT * 8;                        // 32*50*8 floats

    hipLaunchKernelGGL(prep_kernel, dim3(NB), dim3(64), 0, stream,
                       target, nvalid, tA, tB, out);
    hipLaunchKernelGGL(cell_kernel, dim3(NB * 40), dim3(256), 0, stream,
                       output, tA, tB, nvalid, out);
}